// Round 1
// 702.627 us; speedup vs baseline: 1.1569x; 1.1569x over previous
//
#include <hip/hip_runtime.h>
#include <hip/hip_bf16.h>
#include <stdint.h>

#define BB 64
#define SS 2048
#define TT 128
#define GRP 6              // renorm interval AND em prefetch group (6*10.8 < 88.7 e-folds)

typedef __bf16 bf16x8 __attribute__((ext_vector_type(8)));
typedef float  f32x4  __attribute__((ext_vector_type(4)));

// Raw workgroup barrier that does NOT drain vmcnt (LDS ordering only):
// keeps the grouped em prefetch in flight across the per-step barrier.
__device__ __forceinline__ void wg_barrier_lds() {
    asm volatile("" ::: "memory");
    __builtin_amdgcn_s_waitcnt(0xc07f);   // lgkmcnt(0), vmcnt/expcnt no-wait
    __builtin_amdgcn_s_barrier();
    asm volatile("" ::: "memory");
}

// ---- bool-layout detection: mask[0,0] is always true (len >= 1024) ----
__device__ __forceinline__ int detect_mode(const void* maskp) {
    uint32_t w0 = ((const uint32_t*)maskp)[0];
    if (w0 == 1u) return 0;
    if (w0 == 0x3F800000u) return 2;
    if (w0 == 0x3F803F80u) return 3;
    return 1;
}
__device__ __forceinline__ int mask_at(const void* maskp, int mode, size_t idx) {
    if (mode == 0) return ((const int*)maskp)[idx] != 0;
    if (mode == 1) return ((const unsigned char*)maskp)[idx] != 0;
    if (mode == 2) return ((const float*)maskp)[idx] != 0.f;
    return ((const unsigned short*)maskp)[idx] != 0;
}

// ---- fwd+bwd split scan, ONE batch per block, 8 waves (512 threads) ----
// Waves 0-3: forward alpha chain (A = E^T), steps 1..m.
// Waves 4-7: backward beta chain  (A = E),   steps len-1 down to m+1.
// Critical path halves (2047 -> ~1024 slots); the two chains share each SIMD
// (wave i and wave i+4 on SIMD i), so one chain's stalls hide under the other.
// Combine: z = Cf + Cb + log( sum_j u_m[j] * v_m[j] ).
__global__ __launch_bounds__(512, 1) void scan_kernel(
    const float* __restrict__ em, const void* __restrict__ maskp,
    const int* __restrict__ tags, const void* __restrict__ forb,
    const float* __restrict__ trans,
    const float* __restrict__ startt, const float* __restrict__ endt,
    double* __restrict__ zout, double* __restrict__ postout)
{
    const int t = threadIdx.x;
    const int w = t >> 6;          // wave 0..7
    const int lane = t & 63;
    const int q = lane >> 4;       // quad 0..3
    const int c = lane & 15;       // MFMA n-column (all columns replicate batch b)
    const int b = blockIdx.x;      // the batch
    const bool isF = (w < 4);      // chain: fwd (waves 0-3) / bwd (waves 4-7)
    const int ch = isF ? 0 : 1;
    const int w4 = w & 3;

    __shared__ __bf16 uS[2][2][TT];            // [chain][dbuf][tag], bf16
    __shared__ __align__(16) float wred[2][4]; // per-chain per-wave reduction slots
    __shared__ int    redi[8];
    __shared__ double redd[8];
    __shared__ int    redc[8];
    __shared__ float  MinitF, MinitB;
    __shared__ double CdS[2];
    __shared__ float  pendS[2];

    const int mode = detect_mode(maskp);

    // ---- length of this batch (contiguous mask prefix) ----
    {
        int cnt = 0;
        for (int s = t; s < SS; s += 512) cnt += mask_at(maskp, mode, (size_t)b * SS + s);
        #pragma unroll
        for (int off = 32; off >= 1; off >>= 1) cnt += __shfl_xor(cnt, off);
        if (lane == 0) redi[w] = cnt;
    }
    __syncthreads();
    int len = 0;
    #pragma unroll
    for (int i = 0; i < 8; ++i) len += redi[i];

    const int mS     = len >> 1;       // split point
    const int stepsF = mS;             // fwd produces u_1..u_m
    const int stepsB = len - 1 - mS;   // bwd produces y_{len-2}..y_{m+1}, v_m
    const int slots  = stepsF;         // stepsF >= stepsB (diff <= 1)

    // ---- A-fragments: fwd uses E^T, bwd uses E (register-resident whole scan) ----
    // fwd: A[m=c][k=8q+jj] of tile (2*w4+ml, kt) = E[32kt+8q+jj][32w4+16ml+c]
    // bwd: A[m=c][k=8q+jj] of tile (2*w4+ml, kt) = E[32w4+16ml+c][32kt+8q+jj]
    bf16x8 afrag[2][4];
    #pragma unroll
    for (int ml = 0; ml < 2; ++ml) {
        #pragma unroll
        for (int kt = 0; kt < 4; ++kt) {
            #pragma unroll
            for (int jj = 0; jj < 8; ++jj) {
                int row = isF ? (32 * kt + 8 * q + jj) : (32 * w4 + 16 * ml + c);
                int col = isF ? (32 * w4 + 16 * ml + c) : (32 * kt + 8 * q + jj);
                size_t idx = (size_t)row * TT + col;
                afrag[ml][kt][jj] = mask_at(forb, mode, idx) ? (__bf16)0.f
                                                             : (__bf16)__expf(trans[idx]);
            }
        }
    }

    const float* emB = em + (size_t)b * SS * TT;

    // ---- inits: u0 = exp(start + em[0] - Mf);  y_{len-1} = exp(end + em[len-1] - Mb) ----
    if (t < 16) {
        float a[8]; float mx = -1e30f;
        #pragma unroll
        for (int jj = 0; jj < 8; ++jj) {
            int j = t * 8 + jj;
            a[jj] = startt[j] + emB[j];
            mx = fmaxf(mx, a[jj]);
        }
        mx = fmaxf(mx, __shfl_xor(mx, 1)); mx = fmaxf(mx, __shfl_xor(mx, 2));
        mx = fmaxf(mx, __shfl_xor(mx, 4)); mx = fmaxf(mx, __shfl_xor(mx, 8));
        union { __bf16 h[8]; uint4 v; } pk;
        #pragma unroll
        for (int jj = 0; jj < 8; ++jj) pk.h[jj] = (__bf16)__expf(a[jj] - mx);
        *(uint4*)&uS[0][0][t * 8] = pk.v;
        if (t == 0) MinitF = mx;
    }
    if (w == 4 && lane < 16) {
        float a[8]; float mx = -1e30f;
        const float* emL = emB + (size_t)(len - 1) * TT;
        #pragma unroll
        for (int jj = 0; jj < 8; ++jj) {
            int j = lane * 8 + jj;
            a[jj] = endt[j] + emL[j];
            mx = fmaxf(mx, a[jj]);
        }
        mx = fmaxf(mx, __shfl_xor(mx, 1)); mx = fmaxf(mx, __shfl_xor(mx, 2));
        mx = fmaxf(mx, __shfl_xor(mx, 4)); mx = fmaxf(mx, __shfl_xor(mx, 8));
        union { __bf16 h[8]; uint4 v; } pk;
        #pragma unroll
        for (int jj = 0; jj < 8; ++jj) pk.h[jj] = (__bf16)__expf(a[jj] - mx);
        *(uint4*)&uS[1][0][lane * 8] = pk.v;
        if (lane == 0) MinitB = mx;
    }
    __syncthreads();

    double Cd = (double)(isF ? MinitF : MinitB);
    float pending = 1.0f;

    const int tag0 = 32 * w4 + 4 * q;  // this lane's D rows (ml=0)
    const int tag1 = tag0 + 16;        // (ml=1)

    int cur = 0;

    // one scan step; em values for the step already in registers.
    // active=false (bwd filler slot): barrier only, state untouched.
    // scaleEm=false: bwd's final step produces v_m without e_m (it's in u_m).
    auto stepfn = [&](float4 e0, float4 e1, bool ren, bool active, bool scaleEm) {
        float v00, v01, v02, v03, v10, v11, v12, v13;
        if (active) {
            const __bf16* ub = &uS[ch][cur][0];
            bf16x8 bf0 = *(const bf16x8*)(ub + 8 * q);        // same addr across c: broadcast
            bf16x8 bf1 = *(const bf16x8*)(ub + 32 + 8 * q);
            bf16x8 bf2 = *(const bf16x8*)(ub + 64 + 8 * q);
            bf16x8 bf3 = *(const bf16x8*)(ub + 96 + 8 * q);

            // scale factors (overlap the LDS wait)
            float sc00 = (scaleEm ? __expf(e0.x) : 1.0f) * pending;
            float sc01 = (scaleEm ? __expf(e0.y) : 1.0f) * pending;
            float sc02 = (scaleEm ? __expf(e0.z) : 1.0f) * pending;
            float sc03 = (scaleEm ? __expf(e0.w) : 1.0f) * pending;
            float sc10 = (scaleEm ? __expf(e1.x) : 1.0f) * pending;
            float sc11 = (scaleEm ? __expf(e1.y) : 1.0f) * pending;
            float sc12 = (scaleEm ? __expf(e1.z) : 1.0f) * pending;
            float sc13 = (scaleEm ? __expf(e1.w) : 1.0f) * pending;

            // 4 independent 2-chains
            f32x4 aA0 = {0,0,0,0}, aB0 = {0,0,0,0}, aA1 = {0,0,0,0}, aB1 = {0,0,0,0};
            aA0 = __builtin_amdgcn_mfma_f32_16x16x32_bf16(afrag[0][0], bf0, aA0, 0, 0, 0);
            aA1 = __builtin_amdgcn_mfma_f32_16x16x32_bf16(afrag[1][0], bf0, aA1, 0, 0, 0);
            aB0 = __builtin_amdgcn_mfma_f32_16x16x32_bf16(afrag[0][2], bf2, aB0, 0, 0, 0);
            aB1 = __builtin_amdgcn_mfma_f32_16x16x32_bf16(afrag[1][2], bf2, aB1, 0, 0, 0);
            aA0 = __builtin_amdgcn_mfma_f32_16x16x32_bf16(afrag[0][1], bf1, aA0, 0, 0, 0);
            aA1 = __builtin_amdgcn_mfma_f32_16x16x32_bf16(afrag[1][1], bf1, aA1, 0, 0, 0);
            aB0 = __builtin_amdgcn_mfma_f32_16x16x32_bf16(afrag[0][3], bf3, aB0, 0, 0, 0);
            aB1 = __builtin_amdgcn_mfma_f32_16x16x32_bf16(afrag[1][3], bf3, aB1, 0, 0, 0);

            v00 = (aA0[0] + aB0[0]) * sc00; v01 = (aA0[1] + aB0[1]) * sc01;
            v02 = (aA0[2] + aB0[2]) * sc02; v03 = (aA0[3] + aB0[3]) * sc03;
            v10 = (aA1[0] + aB1[0]) * sc10; v11 = (aA1[1] + aB1[1]) * sc11;
            v12 = (aA1[2] + aB1[2]) * sc12; v13 = (aA1[3] + aB1[3]) * sc13;

            // write new u (c==0 lanes only; all c columns hold identical values)
            if (c == 0) {
                union { __bf16 h[4]; uint2 v; } p0, p1;
                p0.h[0] = (__bf16)v00; p0.h[1] = (__bf16)v01;
                p0.h[2] = (__bf16)v02; p0.h[3] = (__bf16)v03;
                p1.h[0] = (__bf16)v10; p1.h[1] = (__bf16)v11;
                p1.h[2] = (__bf16)v12; p1.h[3] = (__bf16)v13;
                __bf16* un = &uS[ch][cur ^ 1][0];
                *(uint2*)(un + tag0) = p0.v;
                *(uint2*)(un + tag1) = p1.v;
            }
            if (ren) {
                float mm = fmaxf(fmaxf(fmaxf(v00, v01), fmaxf(v02, v03)),
                                 fmaxf(fmaxf(v10, v11), fmaxf(v12, v13)));
                mm = fmaxf(mm, __shfl_xor(mm, 16));
                mm = fmaxf(mm, __shfl_xor(mm, 32));
                if (lane == 0) wred[ch][w4] = mm;
            }
        }
        wg_barrier_lds();          // ONE block-wide barrier serves both chains
        if (active) {
            if (ren) {
                float4 wm = *(const float4*)wred[ch];
                float M = fmaxf(fmaxf(wm.x, wm.y), fmaxf(wm.z, wm.w));
                pending = 1.0f / M;
                Cd += (double)__logf(M);
            } else {
                pending = 1.0f;
            }
            cur ^= 1;
        }
    };

    // em row needed at slot s:  fwd -> 1+s (ascending), bwd -> len-2-s (descending).
    // Prefetch overshoot stays in [0,SS): fwd <= slots+GRP <= 1030; bwd >= stepsB-GRP >= 505.
    int k = 0;
    float4 emc0[GRP], emc1[GRP];
    #pragma unroll
    for (int g = 0; g < GRP; ++g) {
        int kk = isF ? (1 + g) : (len - 2 - g);
        emc0[g] = *(const float4*)(emB + (size_t)kk * TT + tag0);
        emc1[g] = *(const float4*)(emB + (size_t)kk * TT + tag1);
    }

    while (k + GRP <= slots) {
        float4 emn0[GRP], emn1[GRP];
        #pragma unroll
        for (int g = 0; g < GRP; ++g) {
            int kk = isF ? (1 + k + GRP + g) : (len - 2 - (k + GRP + g));
            emn0[g] = *(const float4*)(emB + (size_t)kk * TT + tag0);
            emn1[g] = *(const float4*)(emB + (size_t)kk * TT + tag1);
        }
        #pragma unroll
        for (int g = 0; g < GRP; ++g) {
            int s = k + g;
            stepfn(emc0[g], emc1[g], g == GRP - 1,
                   isF || (s < stepsB), isF || (s != stepsB - 1));
        }
        #pragma unroll
        for (int g = 0; g < GRP; ++g) { emc0[g] = emn0[g]; emc1[g] = emn1[g]; }
        k += GRP;
    }

    // ---- tail slots (<GRP), renorm every step ----
    while (k < slots) {
        int kk = isF ? (1 + k) : (len - 2 - k);
        float4 e0 = *(const float4*)(emB + (size_t)kk * TT + tag0);
        float4 e1 = *(const float4*)(emB + (size_t)kk * TT + tag1);
        stepfn(e0, e1, true, isF || (k < stepsB), isF || (k != stepsB - 1));
        ++k;
    }

    // ---- combine: z = Cf + Cb + log( pf * pb * sum_j u_m[j] * v_m[j] ) ----
    __syncthreads();   // full drain once before epilogue
    if (t == 0)        { CdS[0] = Cd; pendS[0] = pending; }
    else if (t == 256) { CdS[1] = Cd; pendS[1] = pending; }
    __syncthreads();
    if (w == 0) {
        const int curF = stepsF & 1;   // cur toggles once per active step
        const int curB = stepsB & 1;
        float sv = (float)uS[0][curF][lane]      * (float)uS[1][curB][lane]
                 + (float)uS[0][curF][lane + 64] * (float)uS[1][curB][lane + 64];
        #pragma unroll
        for (int off = 32; off >= 1; off >>= 1) sv += __shfl_xor(sv, off);
        if (lane == 0)
            zout[b] = CdS[0] + CdS[1]
                    + log((double)pendS[0] * (double)pendS[1] * (double)sv);
    }
    __syncthreads();

    // ---- posterior path score for this batch (512 threads strided) ----
    {
        const int* tg = tags + (size_t)b * SS;
        double local = 0.0; int fcnt = 0;
        for (int kk = 1 + t; kk < len; kk += 512) {
            int tp = tg[kk - 1], tc = tg[kk];
            if (mask_at(forb, mode, (size_t)tp * TT + tc)) fcnt++;
            else local += (double)trans[tp * TT + tc];
            local += (double)emB[(size_t)kk * TT + tc];
        }
        if (t == 0) {
            local += (double)startt[tg[0]] + (double)emB[tg[0]];
            local += (double)endt[tg[len - 1]];
        }
        #pragma unroll
        for (int off = 32; off >= 1; off >>= 1) {
            local += __shfl_xor(local, off);
            fcnt  += __shfl_xor(fcnt, off);
        }
        if (lane == 0) { redd[w] = local; redc[w] = fcnt; }
        __syncthreads();
        if (t == 0) {
            double tot = 0.0; int fc = 0;
            #pragma unroll
            for (int i = 0; i < 8; ++i) { tot += redd[i]; fc += redc[i]; }
            postout[b] = tot - 100000.0 * (double)fc;
        }
    }
}

// ---- nll = mean(post) - mean(z) ----
__global__ void fin_kernel(const double* __restrict__ z, const double* __restrict__ post,
                           float* __restrict__ out) {
    int t = threadIdx.x; // 64 threads, 1 wave
    double pv = post[t];
    double zv = z[t];
    #pragma unroll
    for (int off = 32; off >= 1; off >>= 1) {
        pv += __shfl_xor(pv, off);
        zv += __shfl_xor(zv, off);
    }
    if (t == 0) out[0] = (float)((pv - zv) / (double)BB);
}

extern "C" void kernel_launch(void* const* d_in, const int* in_sizes, int n_in,
                              void* d_out, int out_size, void* d_ws, size_t ws_size,
                              hipStream_t stream) {
    const float* em     = (const float*)d_in[0];
    const void*  maskp  = d_in[1];
    const int*   tags   = (const int*)d_in[2];
    const void*  forb   = d_in[3];
    const float* trans  = (const float*)d_in[4];
    const float* startt = (const float*)d_in[5];
    const float* endt   = (const float*)d_in[6];

    double* z    = (double*)d_ws;            // 64 doubles
    double* post = z + BB;                   // 64 doubles

    scan_kernel<<<BB, 512, 0, stream>>>(em, maskp, tags, forb, trans, startt, endt, z, post);
    fin_kernel<<<1, 64, 0, stream>>>(z, post, (float*)d_out);
}

// Round 2
// 496.151 us; speedup vs baseline: 1.6383x; 1.4162x over previous
//
#include <hip/hip_runtime.h>
#include <hip/hip_bf16.h>
#include <stdint.h>

#define BB 64
#define SS 2048
#define TT 128
#define GRP 6              // renorm interval AND em prefetch group (6*10.8 < 88.7 e-folds)

typedef __bf16 bf16x8 __attribute__((ext_vector_type(8)));
typedef float  f32x4  __attribute__((ext_vector_type(4)));

// Raw workgroup barrier that does NOT drain vmcnt (LDS ordering only):
// keeps the grouped em prefetch in flight across the per-step barrier.
__device__ __forceinline__ void wg_barrier_lds() {
    asm volatile("" ::: "memory");
    __builtin_amdgcn_s_waitcnt(0xc07f);   // lgkmcnt(0), vmcnt/expcnt no-wait
    __builtin_amdgcn_s_barrier();
    asm volatile("" ::: "memory");
}

// ---- bool-layout detection: mask[0,0] is always true (len >= 1024) ----
__device__ __forceinline__ int detect_mode(const void* maskp) {
    uint32_t w0 = ((const uint32_t*)maskp)[0];
    if (w0 == 1u) return 0;
    if (w0 == 0x3F800000u) return 2;
    if (w0 == 0x3F803F80u) return 3;
    return 1;
}
__device__ __forceinline__ int mask_at(const void* maskp, int mode, size_t idx) {
    if (mode == 0) return ((const int*)maskp)[idx] != 0;
    if (mode == 1) return ((const unsigned char*)maskp)[idx] != 0;
    if (mode == 2) return ((const float*)maskp)[idx] != 0.f;
    return ((const unsigned short*)maskp)[idx] != 0;
}

// ---- one chain per block: blocks 0..63 = forward (A=E^T), 64..127 = backward (A=E) ----
// 4 waves / 256 threads per block, 1 wave/SIMD — round-0's measured 366 ns/step
// structure, but on a ~len/2 chain. fwd computes u_m = scaled alpha_m; bwd computes
// v_m = scaled E·y_{m+1} (beta_m without e_m). Combine in fin_kernel:
//   z = Cf + Cb + log( pf * pb * sum_j u_m[j] * v_m[j] )
__global__ __launch_bounds__(256, 1) void scan_kernel(
    const float* __restrict__ em, const void* __restrict__ maskp,
    const int* __restrict__ tags, const void* __restrict__ forb,
    const float* __restrict__ trans,
    const float* __restrict__ startt, const float* __restrict__ endt,
    double* __restrict__ CdW, float* __restrict__ pendW,
    float* __restrict__ uMW, double* __restrict__ postout)
{
    const int t = threadIdx.x;
    const int w = t >> 6;          // wave 0..3 (owns output rows 32w..32w+31)
    const int lane = t & 63;
    const int q = lane >> 4;       // quad 0..3
    const int c = lane & 15;       // MFMA n-column (all columns replicate)
    const int bid = blockIdx.x;
    const bool isF = (bid < BB);
    const int b = isF ? bid : bid - BB;

    __shared__ __bf16 uS[2][TT];               // double-buffered state (bf16)
    __shared__ __align__(16) float wred[4];    // per-wave reduction slots
    __shared__ int    redi[4];
    __shared__ double redd[4];
    __shared__ int    redc[4];
    __shared__ float  Minit;

    const int mode = detect_mode(maskp);

    // ---- length of this batch (contiguous mask prefix) ----
    {
        int cnt = 0;
        for (int s = t; s < SS; s += 256) cnt += mask_at(maskp, mode, (size_t)b * SS + s);
        #pragma unroll
        for (int off = 32; off >= 1; off >>= 1) cnt += __shfl_xor(cnt, off);
        if (lane == 0) redi[w] = cnt;
    }
    __syncthreads();
    const int len = redi[0] + redi[1] + redi[2] + redi[3];

    const int mS    = len >> 1;            // split point
    const int steps = isF ? mS             // fwd: u_1..u_m
                          : (len - 1 - mS);// bwd: y_{len-2}..y_{m+1}, then v_m

    // ---- A-fragments: fwd uses E^T, bwd uses E (register-resident whole scan) ----
    // fwd: A[m=c][k=8q+jj] of tile (2w+ml, kt) = E[32kt+8q+jj][32w+16ml+c]
    // bwd: A[m=c][k=8q+jj] of tile (2w+ml, kt) = E[32w+16ml+c][32kt+8q+jj]
    bf16x8 afrag[2][4];
    #pragma unroll
    for (int ml = 0; ml < 2; ++ml) {
        #pragma unroll
        for (int kt = 0; kt < 4; ++kt) {
            #pragma unroll
            for (int jj = 0; jj < 8; ++jj) {
                int row = isF ? (32 * kt + 8 * q + jj) : (32 * w + 16 * ml + c);
                int col = isF ? (32 * w + 16 * ml + c) : (32 * kt + 8 * q + jj);
                size_t idx = (size_t)row * TT + col;
                afrag[ml][kt][jj] = mask_at(forb, mode, idx) ? (__bf16)0.f
                                                             : (__bf16)__expf(trans[idx]);
            }
        }
    }

    const float* emB = em + (size_t)b * SS * TT;

    // ---- init: fwd u0 = exp(start + em[0] - M); bwd y_{len-1} = exp(end + em[len-1] - M) ----
    if (t < 16) {
        const float* base = isF ? startt : endt;
        const float* emI  = emB + (isF ? 0 : (size_t)(len - 1) * TT);
        float a[8]; float mx = -1e30f;
        #pragma unroll
        for (int jj = 0; jj < 8; ++jj) {
            int j = t * 8 + jj;
            a[jj] = base[j] + emI[j];
            mx = fmaxf(mx, a[jj]);
        }
        mx = fmaxf(mx, __shfl_xor(mx, 1)); mx = fmaxf(mx, __shfl_xor(mx, 2));
        mx = fmaxf(mx, __shfl_xor(mx, 4)); mx = fmaxf(mx, __shfl_xor(mx, 8));
        union { __bf16 h[8]; uint4 v; } pk;
        #pragma unroll
        for (int jj = 0; jj < 8; ++jj) pk.h[jj] = (__bf16)__expf(a[jj] - mx);
        *(uint4*)&uS[0][t * 8] = pk.v;
        if (t == 0) Minit = mx;
    }
    __syncthreads();

    double Cd = (double)Minit;
    float pending = 1.0f;

    const int tag0 = 32 * w + 4 * q;   // this lane's D rows (ml=0)
    const int tag1 = tag0 + 16;        // (ml=1)

    int cur = 0;

    // one scan step; em values already in registers.
    // scaleEm=false only on bwd's final step (v_m = E·y_{m+1}, e_m lives in u_m).
    auto stepfn = [&](float4 e0, float4 e1, bool ren, bool scaleEm) {
        const __bf16* ub = &uS[cur][0];
        bf16x8 bf0 = *(const bf16x8*)(ub + 8 * q);        // same addr across c: broadcast
        bf16x8 bf1 = *(const bf16x8*)(ub + 32 + 8 * q);
        bf16x8 bf2 = *(const bf16x8*)(ub + 64 + 8 * q);
        bf16x8 bf3 = *(const bf16x8*)(ub + 96 + 8 * q);

        // scale factors (overlap the LDS wait)
        float sc00 = (scaleEm ? __expf(e0.x) : 1.0f) * pending;
        float sc01 = (scaleEm ? __expf(e0.y) : 1.0f) * pending;
        float sc02 = (scaleEm ? __expf(e0.z) : 1.0f) * pending;
        float sc03 = (scaleEm ? __expf(e0.w) : 1.0f) * pending;
        float sc10 = (scaleEm ? __expf(e1.x) : 1.0f) * pending;
        float sc11 = (scaleEm ? __expf(e1.y) : 1.0f) * pending;
        float sc12 = (scaleEm ? __expf(e1.z) : 1.0f) * pending;
        float sc13 = (scaleEm ? __expf(e1.w) : 1.0f) * pending;

        // 4 independent 2-chains
        f32x4 aA0 = {0,0,0,0}, aB0 = {0,0,0,0}, aA1 = {0,0,0,0}, aB1 = {0,0,0,0};
        aA0 = __builtin_amdgcn_mfma_f32_16x16x32_bf16(afrag[0][0], bf0, aA0, 0, 0, 0);
        aA1 = __builtin_amdgcn_mfma_f32_16x16x32_bf16(afrag[1][0], bf0, aA1, 0, 0, 0);
        aB0 = __builtin_amdgcn_mfma_f32_16x16x32_bf16(afrag[0][2], bf2, aB0, 0, 0, 0);
        aB1 = __builtin_amdgcn_mfma_f32_16x16x32_bf16(afrag[1][2], bf2, aB1, 0, 0, 0);
        aA0 = __builtin_amdgcn_mfma_f32_16x16x32_bf16(afrag[0][1], bf1, aA0, 0, 0, 0);
        aA1 = __builtin_amdgcn_mfma_f32_16x16x32_bf16(afrag[1][1], bf1, aA1, 0, 0, 0);
        aB0 = __builtin_amdgcn_mfma_f32_16x16x32_bf16(afrag[0][3], bf3, aB0, 0, 0, 0);
        aB1 = __builtin_amdgcn_mfma_f32_16x16x32_bf16(afrag[1][3], bf3, aB1, 0, 0, 0);

        float v00 = (aA0[0] + aB0[0]) * sc00, v01 = (aA0[1] + aB0[1]) * sc01;
        float v02 = (aA0[2] + aB0[2]) * sc02, v03 = (aA0[3] + aB0[3]) * sc03;
        float v10 = (aA1[0] + aB1[0]) * sc10, v11 = (aA1[1] + aB1[1]) * sc11;
        float v12 = (aA1[2] + aB1[2]) * sc12, v13 = (aA1[3] + aB1[3]) * sc13;

        // write new u (c==0 lanes only; all c columns hold identical values)
        if (c == 0) {
            union { __bf16 h[4]; uint2 v; } p0, p1;
            p0.h[0] = (__bf16)v00; p0.h[1] = (__bf16)v01;
            p0.h[2] = (__bf16)v02; p0.h[3] = (__bf16)v03;
            p1.h[0] = (__bf16)v10; p1.h[1] = (__bf16)v11;
            p1.h[2] = (__bf16)v12; p1.h[3] = (__bf16)v13;
            __bf16* un = &uS[cur ^ 1][0];
            *(uint2*)(un + tag0) = p0.v;
            *(uint2*)(un + tag1) = p1.v;
        }
        if (ren) {
            float m = fmaxf(fmaxf(fmaxf(v00, v01), fmaxf(v02, v03)),
                            fmaxf(fmaxf(v10, v11), fmaxf(v12, v13)));
            m = fmaxf(m, __shfl_xor(m, 16));
            m = fmaxf(m, __shfl_xor(m, 32));
            if (lane == 0) wred[w] = m;
        }
        wg_barrier_lds();          // LDS-only barrier: em prefetch stays in flight
        if (ren) {
            float4 wm = *(const float4*)wred;
            float M = fmaxf(fmaxf(wm.x, wm.y), fmaxf(wm.z, wm.w));
            pending = 1.0f / M;
            Cd += (double)__logf(M);
        } else {
            pending = 1.0f;
        }
        cur ^= 1;
    };

    // em row needed at slot s:  fwd -> 1+s (ascending), bwd -> len-2-s (descending).
    // Overshoot stays in [0,SS): fwd <= mS+2*GRP <= 1036; bwd >= mS-GRP >= 506.
    int k = 0;
    float4 emc0[GRP], emc1[GRP];
    #pragma unroll
    for (int g = 0; g < GRP; ++g) {
        int kk = isF ? (1 + g) : (len - 2 - g);
        emc0[g] = *(const float4*)(emB + (size_t)kk * TT + tag0);
        emc1[g] = *(const float4*)(emB + (size_t)kk * TT + tag1);
    }

    while (k + GRP <= steps) {
        float4 emn0[GRP], emn1[GRP];
        #pragma unroll
        for (int g = 0; g < GRP; ++g) {
            int kk = isF ? (1 + k + GRP + g) : (len - 2 - (k + GRP + g));
            emn0[g] = *(const float4*)(emB + (size_t)kk * TT + tag0);
            emn1[g] = *(const float4*)(emB + (size_t)kk * TT + tag1);
        }
        #pragma unroll
        for (int g = 0; g < GRP; ++g)
            stepfn(emc0[g], emc1[g], g == GRP - 1, isF || (k + g != steps - 1));
        #pragma unroll
        for (int g = 0; g < GRP; ++g) { emc0[g] = emn0[g]; emc1[g] = emn1[g]; }
        k += GRP;
    }

    // ---- tail steps (<GRP), renorm every step ----
    while (k < steps) {
        int kk = isF ? (1 + k) : (len - 2 - k);
        float4 e0 = *(const float4*)(emB + (size_t)kk * TT + tag0);
        float4 e1 = *(const float4*)(emB + (size_t)kk * TT + tag1);
        stepfn(e0, e1, true, isF || (k != steps - 1));
        ++k;
    }

    // ---- dump state for the combine kernel ----
    // last stepfn ended with a barrier, so uS[cur] is coherent
    if (t < TT) uMW[(size_t)(isF ? 0 : BB) * TT + (size_t)b * TT + t] = (float)uS[cur][t];
    if (t == 0) { CdW[(isF ? 0 : BB) + b] = Cd; pendW[(isF ? 0 : BB) + b] = pending; }

    // ---- posterior path score (fwd blocks only; 256 threads strided) ----
    if (isF) {
        const int* tg = tags + (size_t)b * SS;
        double local = 0.0; int fcnt = 0;
        for (int kk = 1 + t; kk < len; kk += 256) {
            int tp = tg[kk - 1], tc = tg[kk];
            if (mask_at(forb, mode, (size_t)tp * TT + tc)) fcnt++;
            else local += (double)trans[tp * TT + tc];
            local += (double)emB[(size_t)kk * TT + tc];
        }
        if (t == 0) {
            local += (double)startt[tg[0]] + (double)emB[tg[0]];
            local += (double)endt[tg[len - 1]];
        }
        #pragma unroll
        for (int off = 32; off >= 1; off >>= 1) {
            local += __shfl_xor(local, off);
            fcnt  += __shfl_xor(fcnt, off);
        }
        if (lane == 0) { redd[w] = local; redc[w] = fcnt; }
        __syncthreads();
        if (t == 0) {
            double tot = redd[0] + redd[1] + redd[2] + redd[3];
            int fc = redc[0] + redc[1] + redc[2] + redc[3];
            postout[b] = tot - 100000.0 * (double)fc;
        }
    }
}

// ---- combine: z[b] = Cf + Cb + log(pf*pb*dot(uF,uB)); nll = mean(post) - mean(z) ----
__global__ __launch_bounds__(1024) void fin_kernel(
    const double* __restrict__ CdW, const float* __restrict__ pendW,
    const float* __restrict__ uMW, const double* __restrict__ post,
    float* __restrict__ out)
{
    __shared__ double zS[BB];
    const int t = threadIdx.x, wv = t >> 6, lane = t & 63;
    for (int b = wv; b < BB; b += 16) {
        const float* uF = uMW + (size_t)b * TT;
        const float* uB = uMW + (size_t)(BB + b) * TT;
        float s = uF[lane] * uB[lane] + uF[lane + 64] * uB[lane + 64];
        #pragma unroll
        for (int off = 32; off >= 1; off >>= 1) s += __shfl_xor(s, off);
        if (lane == 0)
            zS[b] = CdW[b] + CdW[BB + b]
                  + log((double)pendW[b] * (double)pendW[BB + b] * (double)s);
    }
    __syncthreads();
    if (t < 64) {
        double pv = post[t];
        double zv = zS[t];
        #pragma unroll
        for (int off = 32; off >= 1; off >>= 1) {
            pv += __shfl_xor(pv, off);
            zv += __shfl_xor(zv, off);
        }
        if (t == 0) out[0] = (float)((pv - zv) / (double)BB);
    }
}

extern "C" void kernel_launch(void* const* d_in, const int* in_sizes, int n_in,
                              void* d_out, int out_size, void* d_ws, size_t ws_size,
                              hipStream_t stream) {
    const float* em     = (const float*)d_in[0];
    const void*  maskp  = d_in[1];
    const int*   tags   = (const int*)d_in[2];
    const void*  forb   = d_in[3];
    const float* trans  = (const float*)d_in[4];
    const float* startt = (const float*)d_in[5];
    const float* endt   = (const float*)d_in[6];

    double* post  = (double*)d_ws;             // 64 doubles
    double* CdW   = post + BB;                 // 128 doubles (fwd | bwd)
    float*  pendW = (float*)(CdW + 2 * BB);    // 128 floats
    float*  uMW   = pendW + 2 * BB;            // 128*128 floats (fwd states | bwd states)

    scan_kernel<<<2 * BB, 256, 0, stream>>>(em, maskp, tags, forb, trans, startt, endt,
                                            CdW, pendW, uMW, post);
    fin_kernel<<<1, 1024, 0, stream>>>(CdW, pendW, uMW, post, (float*)d_out);
}